// Round 1
// baseline (251.863 us; speedup 1.0000x reference)
//
#include <hip/hip_runtime.h>
#include <hip/hip_cooperative_groups.h>
#include <stdint.h>

namespace cg = cooperative_groups;

#define HH 8192           // B*H = 16*512 strip height
#define WW 512            // width
#define WPR 8             // uint64 words per row (512/64)
#define NWORDS (HH * WPR) // 65536
#define TG22F 0.4142135623730951f

// ---- workspace layout (bytes) ----
// packed u16 mag|dir<<12 : 8 MiB   @ 0
// bufA (strong/ping)     : 512 KiB @ 8388608
// weak bitmap            : 512 KiB @ 8912896
// bufB (pong)            : 512 KiB @ 9437184
// result bitmap          : 512 KiB @ 9961472
// flags (512 x 16 ints)  : 32 KiB  @ 10485760

__device__ __forceinline__ float to_img(float v) {
    float t = floorf((v + 1.0f) * 0.5f * 255.0f);
    return fminf(fmaxf(t, 0.0f), 255.0f);
}

__device__ __forceinline__ float ld_img(const float* __restrict__ in, int y, int x, int c) {
    int b = y >> 9;          // image index in strip
    int h = y & 511;
    return to_img(in[(((b * 3 + c) << 9) + h) * 512 + x]);
}

// Kernel 1: Sobel (replicate pad on strip) + channel argmax + direction class.
// packed[y*512+x] = mag | (dir<<12); mag exact integer <= 2040, dir in 0..3
__global__ void k_sobel(const float* __restrict__ in, uint16_t* __restrict__ packed) {
    int y = blockIdx.x >> 1;
    int x = ((blockIdx.x & 1) << 8) + threadIdx.x;
    int ym = y > 0 ? y - 1 : 0;
    int yp = y < HH - 1 ? y + 1 : HH - 1;
    int xm = x > 0 ? x - 1 : 0;
    int xp = x < WW - 1 ? x + 1 : WW - 1;

    float bestMag = -1.0f, bgx = 0.0f, bgy = 0.0f;
    #pragma unroll
    for (int c = 0; c < 3; ++c) {
        float a00 = ld_img(in, ym, xm, c), a01 = ld_img(in, ym, x, c), a02 = ld_img(in, ym, xp, c);
        float a10 = ld_img(in, y,  xm, c),                             a12 = ld_img(in, y,  xp, c);
        float a20 = ld_img(in, yp, xm, c), a21 = ld_img(in, yp, x, c), a22 = ld_img(in, yp, xp, c);
        float gx = (a02 + 2.0f * a12 + a22) - (a00 + 2.0f * a10 + a20);
        float gy = (a20 + 2.0f * a21 + a22) - (a00 + 2.0f * a01 + a02);
        float mg = fabsf(gx) + fabsf(gy);
        if (mg > bestMag) { bestMag = mg; bgx = gx; bgy = gy; } // first-max wins (strict >)
    }
    float ax = fabsf(bgx), ay = fabsf(bgy);
    int dir;
    if (ay < TG22F * ax)          dir = 0;            // horizontal: compare left/right
    else if (ay * TG22F > ax)     dir = 1;            // vertical: compare up/down
    else                          dir = (bgx * bgy >= 0.0f) ? 2 : 3; // diagonals
    int magI = (int)bestMag;                           // exact integer
    packed[y * WW + x] = (uint16_t)(magI | (dir << 12));
}

// Kernel 2: NMS (zero pad on strip) -> strong/weak bitmaps via wave ballot.
__global__ void k_nms(const uint16_t* __restrict__ packed,
                      unsigned long long* __restrict__ strongB,
                      unsigned long long* __restrict__ weakB) {
    int y = blockIdx.x >> 1;
    int x = ((blockIdx.x & 1) << 8) + threadIdx.x;
    uint16_t own = packed[y * WW + x];
    int mag = own & 0xFFF;
    int dir = own >> 12;
    int d1y = (dir == 0) ? 0 : -1;
    int d1x = (dir == 0) ? -1 : (dir == 1) ? 0 : (dir == 2) ? -1 : 1;
    int n1y = y + d1y, n1x = x + d1x;
    int n2y = y - d1y, n2x = x - d1x;
    int n1 = (n1y >= 0 && n1y < HH && n1x >= 0 && n1x < WW) ? (packed[n1y * WW + n1x] & 0xFFF) : 0;
    int n2 = (n2y >= 0 && n2y < HH && n2x >= 0 && n2x < WW) ? (packed[n2y * WW + n2x] & 0xFFF) : 0;
    bool keep = (mag > n1) && (mag >= n2);
    bool strong = keep && (mag > 200);
    bool weak   = keep && (mag > 100);   // includes strong, as in reference
    unsigned long long sb = __ballot(strong ? 1 : 0);
    unsigned long long wb = __ballot(weak ? 1 : 0);
    if ((threadIdx.x & 63) == 0) {
        int word = y * WPR + (x >> 6);
        strongB[word] = sb;
        weakB[word]   = wb;
    }
}

// Kernel 3 (cooperative): synchronous double-buffered 8-connected dilation
// through weak pixels, early exit on fixed point, capped at 512 iters
// (exactly the reference while_loop semantics).
__global__ void k_hyst(const unsigned long long* __restrict__ weakB,
                       unsigned long long* bufA,
                       unsigned long long* bufB,
                       unsigned long long* __restrict__ result,
                       int* __restrict__ flags) {
    cg::grid_group grid = cg::this_grid();
    int tid = blockIdx.x * blockDim.x + threadIdx.x; // 0..NWORDS-1
    int y = tid >> 3;
    int k = tid & 7;
    const unsigned long long wk = weakB[tid];
    unsigned long long* bufs[2] = { bufA, bufB };
    int cur = 0;
    unsigned long long last = 0;
    for (int it = 0; it < 512; ++it) {
        const unsigned long long* src = bufs[cur];
        unsigned long long* dst = bufs[cur ^ 1];
        unsigned long long own = src[tid];
        unsigned long long acc = 0;
        #pragma unroll
        for (int dy = -1; dy <= 1; ++dy) {
            int yy = y + dy;
            if (yy < 0 || yy >= HH) continue;
            const unsigned long long* row = src + yy * WPR;
            unsigned long long c = row[k];
            unsigned long long h = c | (c << 1) | (c >> 1);
            if (k > 0)       h |= row[k - 1] >> 63;
            if (k < WPR - 1) h |= row[k + 1] << 63;
            acc |= h;
        }
        unsigned long long nv = own | (acc & wk);
        dst[tid] = nv;
        last = nv;
        unsigned long long chb = __ballot((nv != own) ? 1 : 0);
        if (chb != 0ull && (threadIdx.x & 63) == 0) {
            __hip_atomic_fetch_or(&flags[it * 16], 1, __ATOMIC_RELAXED, __HIP_MEMORY_SCOPE_AGENT);
        }
        __threadfence();
        grid.sync();
        cur ^= 1;
        int f = __hip_atomic_load(&flags[it * 16], __ATOMIC_RELAXED, __HIP_MEMORY_SCOPE_AGENT);
        if (f == 0) break;   // uniform across grid: all threads read same value
    }
    result[tid] = last;
}

// Kernel 4: expand bitmap -> (16,3,512,512) f32 output in {-1,+1}
__global__ void k_out(const unsigned long long* __restrict__ result, float* __restrict__ out) {
    int t = blockIdx.x * blockDim.x + threadIdx.x; // 0..4194303  (b,h,w)
    int b = t >> 18;
    int r = t & 262143;
    int h = r >> 9;
    int w = r & 511;
    int y = (b << 9) + h;
    unsigned long long word = result[y * WPR + (w >> 6)];
    float v = ((word >> (w & 63)) & 1ull) ? 1.0f : -1.0f;
    int base = (b * 3) << 18;
    int off = (h << 9) + w;
    out[base + off] = v;
    out[base + 262144 + off] = v;
    out[base + 524288 + off] = v;
}

extern "C" void kernel_launch(void* const* d_in, const int* in_sizes, int n_in,
                              void* d_out, int out_size, void* d_ws, size_t ws_size,
                              hipStream_t stream) {
    const float* x = (const float*)d_in[0];
    float* out = (float*)d_out;
    char* ws = (char*)d_ws;

    uint16_t* packed           = (uint16_t*)(ws);
    unsigned long long* bufA   = (unsigned long long*)(ws + 8388608);
    unsigned long long* weakB  = (unsigned long long*)(ws + 8912896);
    unsigned long long* bufB   = (unsigned long long*)(ws + 9437184);
    unsigned long long* result = (unsigned long long*)(ws + 9961472);
    int* flags                 = (int*)(ws + 10485760);

    // flags must start at 0 (ws is poisoned 0xAA each run)
    hipMemsetAsync(flags, 0, 512 * 16 * sizeof(int), stream);

    k_sobel<<<HH * 2, 256, 0, stream>>>(x, packed);
    k_nms<<<HH * 2, 256, 0, stream>>>(packed, bufA, weakB);

    void* args[] = { (void*)&weakB, (void*)&bufA, (void*)&bufB, (void*)&result, (void*)&flags };
    hipLaunchCooperativeKernel(reinterpret_cast<void*>(&k_hyst),
                               dim3(256), dim3(256), args, 0, stream);

    k_out<<<(HH * WW) / 256, 256, 0, stream>>>(result, out);
}